// Round 1
// baseline (11119.607 us; speedup 1.0000x reference)
//
#include <hip/hip_runtime.h>
#include <hip/hip_bf16.h>

// ---------------------------------------------------------------------------
// PPYOLOE head, fp32 baseline.
// Shapes: B=16; scales: (C,H,W) = (1024,20,20),(512,40,40),(256,80,80)
// Outputs (concat in d_out, fp32):
//   cls_score [16,80,8400], reg_dist [16,4,8400], anchors [8400,2], stride [8400]
// ---------------------------------------------------------------------------

#define OUT_REG   10752000ull          // 16*80*8400
#define OUT_ANC   11289600ull          // + 16*4*8400
#define OUT_STR   11306400ull          // + 8400*2

// ---------------- avg pool over H*W ----------------
__global__ void k_avgpool(const float* __restrict__ feat, float* __restrict__ avg, int L) {
    int bc = blockIdx.x;
    const float* p = feat + (size_t)bc * L;
    float s = 0.f;
    for (int i = threadIdx.x; i < L; i += blockDim.x) s += p[i];
#pragma unroll
    for (int off = 32; off > 0; off >>= 1) s += __shfl_down(s, off, 64);
    __shared__ float wsum[4];
    int wid = threadIdx.x >> 6, lane = threadIdx.x & 63;
    if (lane == 0) wsum[wid] = s;
    __syncthreads();
    if (threadIdx.x == 0)
        avg[bc] = (wsum[0] + wsum[1] + wsum[2] + wsum[3]) / (float)L;
}

// ---------------- gate = sigmoid(fc_w @ avg + fc_b), both branches ----------
__global__ void k_gate(const float* __restrict__ avg,
                       const float* __restrict__ fcw_c, const float* __restrict__ fcb_c,
                       const float* __restrict__ fcw_r, const float* __restrict__ fcb_r,
                       float* __restrict__ gc, float* __restrict__ gr, int C) {
    const float* fcw = blockIdx.y ? fcw_r : fcw_c;
    const float* fcb = blockIdx.y ? fcb_r : fcb_c;
    float* g = blockIdx.y ? gr : gc;
    int col = threadIdx.x & 15;   // co within block group of 16
    int b   = threadIdx.x >> 4;   // 16 batches
    int co  = blockIdx.x * 16 + col;
    const float* wrow = fcw + (size_t)co * C;
    const float* arow = avg + (size_t)b * C;
    float s = fcb[co];
    for (int ci = 0; ci < C; ++ci) s += wrow[ci] * arow[ci];
    g[(size_t)b * C + co] = 1.f / (1.f + expf(-s));
}

// ---------------- fused: X = swish(BN(conv1x1(feat*gate))) [+ feat] ---------
// 64(co) x 64(p) tile GEMM, K-chunk 16, 256 threads, 4x4 micro-tile.
template<bool RES>
__global__ __launch_bounds__(256) void k_ese(const float* __restrict__ feat,
                                             const float* __restrict__ gate,
                                             const float* __restrict__ Wm,
                                             const float* __restrict__ bns,
                                             const float* __restrict__ bnb,
                                             float* __restrict__ X, int C, int L) {
    int b  = blockIdx.z;
    int co0 = blockIdx.y * 64;
    int p0  = blockIdx.x * 64;
    __shared__ float As[16][68];
    __shared__ float Bs[16][68];
    int t = threadIdx.x;
    int tco = t >> 4, tp = t & 15;
    float acc[4][4] = {};
    const float* gb = gate + (size_t)b * C;
    const float* fb = feat + (size_t)b * C * L;

    for (int k0 = 0; k0 < C; k0 += 16) {
        { // A tile: As[k][co] = W[co0+co][k0+k] * gate[k0+k]
            int co = t >> 2, k4 = (t & 3) * 4;
            float4 w4 = *(const float4*)(Wm + (size_t)(co0 + co) * C + k0 + k4);
            As[k4 + 0][co] = w4.x * gb[k0 + k4 + 0];
            As[k4 + 1][co] = w4.y * gb[k0 + k4 + 1];
            As[k4 + 2][co] = w4.z * gb[k0 + k4 + 2];
            As[k4 + 3][co] = w4.w * gb[k0 + k4 + 3];
        }
        { // B tile: Bs[k][p] = feat[b][k0+k][p0+p]
            int k = t >> 4, p4 = (t & 15) * 4;
            int p = p0 + p4;
            float4 v = make_float4(0.f, 0.f, 0.f, 0.f);
            if (p < L) v = *(const float4*)(fb + (size_t)(k0 + k) * L + p);
            Bs[k][p4 + 0] = v.x; Bs[k][p4 + 1] = v.y;
            Bs[k][p4 + 2] = v.z; Bs[k][p4 + 3] = v.w;
        }
        __syncthreads();
#pragma unroll
        for (int k = 0; k < 16; ++k) {
            float4 av = *(const float4*)&As[k][tco * 4];
            float4 bv = *(const float4*)&Bs[k][tp * 4];
            acc[0][0] += av.x * bv.x; acc[0][1] += av.x * bv.y;
            acc[0][2] += av.x * bv.z; acc[0][3] += av.x * bv.w;
            acc[1][0] += av.y * bv.x; acc[1][1] += av.y * bv.y;
            acc[1][2] += av.y * bv.z; acc[1][3] += av.y * bv.w;
            acc[2][0] += av.z * bv.x; acc[2][1] += av.z * bv.y;
            acc[2][2] += av.z * bv.z; acc[2][3] += av.z * bv.w;
            acc[3][0] += av.w * bv.x; acc[3][1] += av.w * bv.y;
            acc[3][2] += av.w * bv.z; acc[3][3] += av.w * bv.w;
        }
        __syncthreads();
    }
    // epilogue: BN affine + swish (+ residual), vector store
    int p = p0 + tp * 4;
    if (p < L) {
#pragma unroll
        for (int i = 0; i < 4; ++i) {
            int co = co0 + tco * 4 + i;
            float s = bns[co], bb = bnb[co];
            float4 o;
            float v0 = acc[i][0] * s + bb, v1 = acc[i][1] * s + bb;
            float v2 = acc[i][2] * s + bb, v3 = acc[i][3] * s + bb;
            o.x = v0 / (1.f + __expf(-v0));
            o.y = v1 / (1.f + __expf(-v1));
            o.z = v2 / (1.f + __expf(-v2));
            o.w = v3 / (1.f + __expf(-v3));
            if (RES) {
                float4 r = *(const float4*)(fb + (size_t)co * L + p);
                o.x += r.x; o.y += r.y; o.z += r.z; o.w += r.w;
            }
            *(float4*)(X + ((size_t)b * C + co) * L + p) = o;
        }
    }
}

// ---------------- 3x3 conv, pad=1, M out channels (80 or 68) ----------------
// Tile: 16x8 pixels, all M channels. 256 thr: tco=t>>4 (16 groups x 5 co),
// tp=t&15 -> row=tp>>1, px0=(tp&1)*8. Each thread: 5 co x 8 px.
template<bool SIG>
__global__ __launch_bounds__(256) void k_conv3(const float* __restrict__ X,
                                               const float* __restrict__ Wm,
                                               const float* __restrict__ bias,
                                               float* __restrict__ out,
                                               int C, int H, int W, int M, int tilesX,
                                               size_t chan_stride, size_t base_off,
                                               size_t batch_stride) {
    int b = blockIdx.y;
    int tileX = blockIdx.x % tilesX, tileY = blockIdx.x / tilesX;
    int x0 = tileX * 16, y0 = tileY * 8;
    int t = threadIdx.x;
    int tco = t >> 4;
    int tp = t & 15;
    int py = tp >> 1, px0 = (tp & 1) * 8;
    __shared__ float Xs[8][10][20];     // 8 ci x (8+2) x (16+2, padded 20)
    __shared__ float Ws[80 * 72];       // M co x (8 ci * 9 taps)
    float acc[5][8] = {};
    int L = H * W;
    const float* Xb = X + (size_t)b * C * L;

    for (int c0 = 0; c0 < C; c0 += 8) {
        for (int idx = t; idx < 8 * 180; idx += 256) {
            int ci = idx / 180, r = idx % 180, yy = r / 18, xx = r % 18;
            int gy = y0 + yy - 1, gx = x0 + xx - 1;
            float v = 0.f;
            if (gy >= 0 && gy < H && gx >= 0 && gx < W)
                v = Xb[(size_t)(c0 + ci) * L + gy * W + gx];
            Xs[ci][yy][xx] = v;
        }
        for (int idx = t; idx < M * 72; idx += 256) {
            int co = idx / 72, r = idx % 72;
            Ws[co * 72 + r] = Wm[(size_t)co * C * 9 + (size_t)c0 * 9 + r];
        }
        __syncthreads();
#pragma unroll
        for (int ci = 0; ci < 8; ++ci) {
#pragma unroll
            for (int ky = 0; ky < 3; ++ky) {
                float xr[10];
#pragma unroll
                for (int q = 0; q < 10; ++q) xr[q] = Xs[ci][py + ky][px0 + q];
#pragma unroll
                for (int j = 0; j < 5; ++j) {
                    const float* wp = &Ws[(tco * 5 + j) * 72 + ci * 9 + ky * 3];
                    float w0 = wp[0], w1 = wp[1], w2 = wp[2];
#pragma unroll
                    for (int q = 0; q < 8; ++q)
                        acc[j][q] += w0 * xr[q] + w1 * xr[q + 1] + w2 * xr[q + 2];
                }
            }
        }
        __syncthreads();
    }
    // epilogue
    int gy = y0 + py;
    if (gy < H) {
#pragma unroll
        for (int j = 0; j < 5; ++j) {
            int co = tco * 5 + j;
            if (co >= M) break;
            float bv = bias[co];
            float* op = out + (size_t)b * batch_stride + (size_t)co * chan_stride
                        + base_off + (size_t)gy * W;
            for (int q = 0; q < 8; ++q) {
                int gx = x0 + px0 + q;
                if (gx >= W) break;
                float v = acc[j][q] + bv;
                if (SIG) v = 1.f / (1.f + __expf(-v));
                op[gx] = v;
            }
        }
    }
}

// ---------------- DFL: softmax over 17 bins, integral with proj=0..16 -------
__global__ void k_dfl(const float* __restrict__ logits, float* __restrict__ out,
                      int L, int scale_off) {
    int idx = blockIdx.x * 256 + threadIdx.x;
    int total = 16 * 4 * L;
    if (idx >= total) return;
    int p = idx % L, r = idx / L, f = r & 3, b = r >> 2;
    const float* lp = logits + ((size_t)b * 68 + f * 17) * L + p;
    float v[17], mx = -1e30f;
#pragma unroll
    for (int j = 0; j < 17; ++j) { v[j] = lp[(size_t)j * L]; mx = fmaxf(mx, v[j]); }
    float s = 0.f, d = 0.f;
#pragma unroll
    for (int j = 0; j < 17; ++j) {
        float e = __expf(v[j] - mx);
        s += e; d += e * (float)j;
    }
    out[OUT_REG + ((size_t)b * 4 + f) * 8400 + scale_off + p] = d / s;
}

// ---------------- anchors + stride tensor ----------------
__global__ void k_anchors(float* __restrict__ out) {
    int idx = blockIdx.x * 256 + threadIdx.x;
    if (idx >= 8400) return;
    int w, base; float s;
    if (idx < 400)       { w = 20; s = 32.f; base = 0; }
    else if (idx < 2000) { w = 40; s = 16.f; base = 400; }
    else                 { w = 80; s = 8.f;  base = 2000; }
    int r = idx - base;
    int row = r / w, col = r % w;
    out[OUT_ANC + (size_t)idx * 2]     = (float)col + 0.5f;
    out[OUT_ANC + (size_t)idx * 2 + 1] = (float)row + 0.5f;
    out[OUT_STR + idx] = s;
}

// ---------------------------------------------------------------------------
extern "C" void kernel_launch(void* const* d_in, const int* in_sizes, int n_in,
                              void* d_out, int out_size, void* d_ws, size_t ws_size,
                              hipStream_t stream) {
    const int B = 16;
    static const int Cs[3] = {1024, 512, 256};
    static const int Hs[3] = {20, 40, 80};
    static const int Wd[3] = {20, 40, 80};
    static const int offs[3] = {0, 400, 2000};

    float* ws = (float*)d_ws;
    float* Xbuf   = ws;                       // 26,214,400 floats (max B*C*L)
    float* logits = ws + 26214400;            //  6,963,200 floats (16*68*6400)
    float* avg    = ws + 26214400 + 6963200;  // 16*1024
    float* gcls   = avg  + 16 * 1024;
    float* greg   = gcls + 16 * 1024;
    float* out = (float*)d_out;

    for (int i = 0; i < 3; ++i) {
        const int base = i * 15;
        const float* feat = (const float*)d_in[base + 0];
        const float* cfw  = (const float*)d_in[base + 1];
        const float* cfb  = (const float*)d_in[base + 2];
        const float* ccw  = (const float*)d_in[base + 3];
        const float* cbs  = (const float*)d_in[base + 4];
        const float* cbb  = (const float*)d_in[base + 5];
        const float* rfw  = (const float*)d_in[base + 6];
        const float* rfb  = (const float*)d_in[base + 7];
        const float* rcw  = (const float*)d_in[base + 8];
        const float* rbs  = (const float*)d_in[base + 9];
        const float* rbb  = (const float*)d_in[base + 10];
        const float* pcw  = (const float*)d_in[base + 11];
        const float* pcb  = (const float*)d_in[base + 12];
        const float* prw  = (const float*)d_in[base + 13];
        const float* prb  = (const float*)d_in[base + 14];

        int C = Cs[i], H = Hs[i], W = Wd[i], L = H * W;

        k_avgpool<<<B * C, 256, 0, stream>>>(feat, avg, L);
        k_gate<<<dim3(C / 16, 2), 256, 0, stream>>>(avg, cfw, cfb, rfw, rfb, gcls, greg, C);

        dim3 gg((L + 63) / 64, C / 64, B);
        int tx = (W + 15) / 16, ty = (H + 7) / 8;

        // cls branch: ese(+feat residual) -> conv3x3 -> sigmoid -> d_out
        k_ese<true><<<gg, 256, 0, stream>>>(feat, gcls, ccw, cbs, cbb, Xbuf, C, L);
        k_conv3<true><<<dim3(tx * ty, B), 256, 0, stream>>>(
            Xbuf, pcw, pcb, out, C, H, W, 80, tx,
            (size_t)8400, (size_t)offs[i], (size_t)80 * 8400);

        // reg branch: ese -> conv3x3 -> logits -> softmax+DFL -> d_out
        k_ese<false><<<gg, 256, 0, stream>>>(feat, greg, rcw, rbs, rbb, Xbuf, C, L);
        k_conv3<false><<<dim3(tx * ty, B), 256, 0, stream>>>(
            Xbuf, prw, prb, logits, C, H, W, 68, tx,
            (size_t)L, (size_t)0, (size_t)68 * L);

        int tot = B * 4 * L;
        k_dfl<<<(tot + 255) / 256, 256, 0, stream>>>(logits, out, L, offs[i]);
    }
    k_anchors<<<33, 256, 0, stream>>>(out);
}

// Round 2
// 2358.554 us; speedup vs baseline: 4.7146x; 4.7146x over previous
//
#include <hip/hip_runtime.h>
#include <hip/hip_bf16.h>

// ---------------------------------------------------------------------------
// PPYOLOE head, bf16-MFMA version.
// B=16; scales: (C,H,W) = (1024,20,20),(512,40,40),(256,80,80)
// d_out: cls [16,80,8400] f32 | reg [16,4,8400] f32 | anchors [8400,2] | stride [8400]
// ---------------------------------------------------------------------------

typedef short s8v __attribute__((ext_vector_type(8)));
typedef float f4v __attribute__((ext_vector_type(4)));

#define OUT_REG   10752000ull
#define OUT_ANC   11289600ull
#define OUT_STR   11306400ull

__device__ __forceinline__ unsigned short f2bf(float f) {
    unsigned u = __float_as_uint(f);
    u += 0x7fffu + ((u >> 16) & 1u);
    return (unsigned short)(u >> 16);
}
__device__ __forceinline__ float bf2f(unsigned short h) {
    return __uint_as_float(((unsigned)h) << 16);
}
__device__ __forceinline__ void gl16(const void* g, void* l) {
    __builtin_amdgcn_global_load_lds((const __attribute__((address_space(1))) void*)g,
                                     (__attribute__((address_space(3))) void*)l, 16, 0, 0);
}

// ---------------- zero-fill (for X_pad halo) ----------------
__global__ void k_fill0(uint4* __restrict__ p, long n16) {
    uint4 z = make_uint4(0u, 0u, 0u, 0u);
    for (long i = blockIdx.x * 256 + threadIdx.x; i < n16; i += (long)gridDim.x * 256)
        p[i] = z;
}

// ---------------- avg pool over H*W ----------------
__global__ void k_avgpool(const float* __restrict__ feat, float* __restrict__ avg, int L) {
    int bc = blockIdx.x;
    const float* p = feat + (size_t)bc * L;
    float s = 0.f;
    for (int i = threadIdx.x; i < L; i += blockDim.x) s += p[i];
#pragma unroll
    for (int off = 32; off > 0; off >>= 1) s += __shfl_down(s, off, 64);
    __shared__ float wsum[4];
    int wid = threadIdx.x >> 6, lane = threadIdx.x & 63;
    if (lane == 0) wsum[wid] = s;
    __syncthreads();
    if (threadIdx.x == 0)
        avg[bc] = (wsum[0] + wsum[1] + wsum[2] + wsum[3]) / (float)L;
}

// ---------------- gate = sigmoid(fc_w @ avg + fc_b), both branches ----------
__global__ void k_gate(const float* __restrict__ avg,
                       const float* __restrict__ fcw_c, const float* __restrict__ fcb_c,
                       const float* __restrict__ fcw_r, const float* __restrict__ fcb_r,
                       float* __restrict__ gc, float* __restrict__ gr, int C) {
    const float* fcw = blockIdx.y ? fcw_r : fcw_c;
    const float* fcb = blockIdx.y ? fcb_r : fcb_c;
    float* g = blockIdx.y ? gr : gc;
    int col = threadIdx.x & 15;
    int b   = threadIdx.x >> 4;
    int co  = blockIdx.x * 16 + col;
    const float* wrow = fcw + (size_t)co * C;
    const float* arow = avg + (size_t)b * C;
    float s = fcb[co];
    for (int ci = 0; ci < C; ++ci) s += wrow[ci] * arow[ci];
    g[(size_t)b * C + co] = 1.f / (1.f + expf(-s));
}

// ---------------- weight conversions ----------------
__global__ void k_wcvt(const float* __restrict__ w, unsigned short* __restrict__ o, int n4) {
    for (int i = blockIdx.x * 256 + threadIdx.x; i < n4; i += gridDim.x * 256) {
        float4 v = ((const float4*)w)[i];
        ushort4 u = make_ushort4(f2bf(v.x), f2bf(v.y), f2bf(v.z), f2bf(v.w));
        ((ushort4*)o)[i] = u;
    }
}

// 3x3 weights: src OIHW [co][ci][tap] -> dst [80][tap*C + ci], zero-pad co>=M
__global__ void k_wt3(const float* __restrict__ src, unsigned short* __restrict__ dst,
                      int C, int M, int n) {
    int nineC = 9 * C;
    for (int idx = blockIdx.x * 256 + threadIdx.x; idx < n; idx += gridDim.x * 256) {
        int co = idx / nineC, r = idx - co * nineC;
        int tap = r / C, ci = r - tap * C;
        unsigned short v = 0;
        if (co < M)
            v = f2bf(src[(size_t)co * C * 9 + (size_t)ci * 9 + tap]);
        dst[idx] = v;
    }
}

// ---------------- prep: Bbuf[b][p][ci]=bf16(feat*gate); opt Xpad[p_pad][ci]=bf16(feat)
template<bool WR>
__global__ __launch_bounds__(256) void k_prep(const float* __restrict__ feat,
                                              const float* __restrict__ gate,
                                              unsigned short* __restrict__ Bbuf,
                                              unsigned short* __restrict__ Xpad,
                                              int C, int L, int W, int Wp, int Hp) {
    int b = blockIdx.z, ci0 = blockIdx.y * 32, p0 = blockIdx.x * 32;
    __shared__ float S[32][33];
    int t = threadIdx.x;
    {
        int cil = t >> 3, pl4 = (t & 7) * 4;
        int p = p0 + pl4;
        const float* src = feat + ((size_t)(b * C + ci0 + cil)) * L + p;
        float4 v = make_float4(0.f, 0.f, 0.f, 0.f);
        if (p + 3 < L) v = *(const float4*)src;
        else {
            if (p < L)     v.x = src[0];
            if (p + 1 < L) v.y = src[1];
            if (p + 2 < L) v.z = src[2];
            if (p + 3 < L) v.w = src[3];
        }
        S[cil][pl4] = v.x; S[cil][pl4 + 1] = v.y;
        S[cil][pl4 + 2] = v.z; S[cil][pl4 + 3] = v.w;
    }
    __syncthreads();
    int pl = t >> 3, ci4 = (t & 7) * 4;
    int p = p0 + pl;
    if (p < L) {
        float4 g = *(const float4*)(gate + (size_t)b * C + ci0 + ci4);
        float f0 = S[ci4][pl], f1 = S[ci4 + 1][pl], f2 = S[ci4 + 2][pl], f3 = S[ci4 + 3][pl];
        ushort4 ug = make_ushort4(f2bf(f0 * g.x), f2bf(f1 * g.y), f2bf(f2 * g.z), f2bf(f3 * g.w));
        *(ushort4*)(Bbuf + ((size_t)b * L + p) * C + ci0 + ci4) = ug;
        if (WR) {
            int y = p / W, x = p - y * W;
            ushort4 uf = make_ushort4(f2bf(f0), f2bf(f1), f2bf(f2), f2bf(f3));
            *(ushort4*)(Xpad + (((size_t)b * Hp + 1 + y) * Wp + 1 + x) * C + ci0 + ci4) = uf;
        }
    }
}

// ---------------- ESE 1x1 as MFMA GEMM ----------------
// D[p][co] = sum_ci Bbuf[p][ci] * Wm[co][ci]; epilogue BN+swish (+accum residual)
// tile 128(p) x 128(co), BK=32, 4 waves, each wave 64x64.
template<bool RES>
__global__ __launch_bounds__(256) void k_ese(const unsigned short* __restrict__ Ab,
                                             const unsigned short* __restrict__ Wm,
                                             const float* __restrict__ bns,
                                             const float* __restrict__ bnb,
                                             unsigned short* __restrict__ Xpad,
                                             int C, int L, int W, int Wp, int Hp) {
    int b = blockIdx.z;
    int p0 = blockIdx.x * 128, co0 = blockIdx.y * 128;
    __shared__ unsigned short As[128 * 32];
    __shared__ unsigned short Bs[128 * 32];
    int t = threadIdx.x, lane = t & 63, w = t >> 6;
    int l15 = lane & 15, kg = lane >> 4;
    int mbase = (w >> 1) * 64, nbase = (w & 1) * 64;
    int swb = ((kg ^ (l15 & 3) ^ ((l15 >> 2) & 3)) << 4);     // read slot byte
    int slog = (t & 3) ^ ((t >> 2) & 3) ^ ((t >> 4) & 3);     // stage source slot
    int r = t >> 2;
    size_t aRow = ((size_t)b * L + p0 + r) * C + 8 * slog;
    size_t bRow = ((size_t)(co0 + r)) * C + 8 * slog;
    size_t rstep = (size_t)64 * C;

    f4v acc[4][4];
#pragma unroll
    for (int i = 0; i < 4; ++i)
#pragma unroll
        for (int j = 0; j < 4; ++j) acc[i][j] = {0.f, 0.f, 0.f, 0.f};

    for (int k0 = 0; k0 < C; k0 += 32) {
        gl16(Ab + aRow + k0,         (char*)As + t * 16);
        gl16(Ab + aRow + rstep + k0, (char*)As + 4096 + t * 16);
        gl16(Wm + bRow + k0,         (char*)Bs + t * 16);
        gl16(Wm + bRow + rstep + k0, (char*)Bs + 4096 + t * 16);
        __syncthreads();
        s8v af[4], bv[4];
#pragma unroll
        for (int i = 0; i < 4; ++i)
            af[i] = *(const s8v*)((const char*)As + ((mbase + i * 16 + l15) << 6) + swb);
#pragma unroll
        for (int i = 0; i < 4; ++i)
            bv[i] = *(const s8v*)((const char*)Bs + ((nbase + i * 16 + l15) << 6) + swb);
#pragma unroll
        for (int mf = 0; mf < 4; ++mf)
#pragma unroll
            for (int nf = 0; nf < 4; ++nf)
                acc[mf][nf] = __builtin_amdgcn_mfma_f32_16x16x32_bf16(af[mf], bv[nf], acc[mf][nf], 0, 0, 0);
        __syncthreads();
    }

    // epilogue
    float sv[4], bvv[4];
#pragma unroll
    for (int nf = 0; nf < 4; ++nf) {
        int co = co0 + nbase + nf * 16 + l15;
        sv[nf] = bns[co]; bvv[nf] = bnb[co];
    }
    int cobase = co0 + nbase + l15;
#pragma unroll
    for (int mf = 0; mf < 4; ++mf) {
#pragma unroll
        for (int rg = 0; rg < 4; ++rg) {
            int p = p0 + mbase + mf * 16 + 4 * kg + rg;
            if (p < L) {
                int y = p / W, x = p - y * W;
                size_t rowb = (((size_t)b * Hp + 1 + y) * Wp + 1 + x) * C + cobase;
#pragma unroll
                for (int nf = 0; nf < 4; ++nf) {
                    float v = acc[mf][nf][rg] * sv[nf] + bvv[nf];
                    v = v / (1.f + __expf(-v));
                    unsigned short* dst = Xpad + rowb + nf * 16;
                    if (RES) v += bf2f(*dst);
                    *dst = f2bf(v);
                }
            }
        }
    }
}

// ---------------- 3x3 conv as implicit MFMA GEMM ----------------
// out[co][p] = sum_{tap,ci} Wt[co][tap*C+ci] * Xpad[p_shift(tap)][ci]
// block: 256 pix (4 waves x 64), M=80 (5 m-frags) in regs. Frags direct from L2.
template<bool SIG>
__global__ __launch_bounds__(256) void k_conv3(const unsigned short* __restrict__ Xpad,
                                               const unsigned short* __restrict__ Wt,
                                               const float* __restrict__ bias,
                                               float* __restrict__ out,
                                               int C, int H, int W, int Hp, int Wp, int M,
                                               size_t cstride, size_t boff, size_t bstride) {
    int b = blockIdx.y;
    int L = H * W;
    int t = threadIdx.x, lane = t & 63, w = t >> 6;
    int l15 = lane & 15, kg = lane >> 4;
    int pw0 = blockIdx.x * 256 + w * 64;
    int nineC = 9 * C;

    int   pn[4];
    size_t basen[4];
#pragma unroll
    for (int nf = 0; nf < 4; ++nf) {
        int p = pw0 + nf * 16 + l15;
        pn[nf] = p;
        int pc = p < L ? p : L - 1;
        int y = pc / W, x = pc - y * W;
        basen[nf] = (((size_t)b * Hp + 1 + y) * Wp + 1 + x) * C;
    }

    f4v acc[5][4];
#pragma unroll
    for (int i = 0; i < 5; ++i)
#pragma unroll
        for (int j = 0; j < 4; ++j) acc[i][j] = {0.f, 0.f, 0.f, 0.f};

#pragma unroll
    for (int ky = 0; ky < 3; ++ky) {
#pragma unroll
        for (int kx = 0; kx < 3; ++kx) {
            long toff = (long)((ky - 1) * Wp + (kx - 1)) * C;
            int tapC = (3 * ky + kx) * C;
            for (int ci0 = 0; ci0 < C; ci0 += 32) {
                s8v a[5], bv[4];
#pragma unroll
                for (int mf = 0; mf < 5; ++mf)
                    a[mf] = *(const s8v*)(Wt + (size_t)(mf * 16 + l15) * nineC + tapC + ci0 + 8 * kg);
#pragma unroll
                for (int nf = 0; nf < 4; ++nf)
                    bv[nf] = *(const s8v*)(Xpad + basen[nf] + toff + ci0 + 8 * kg);
#pragma unroll
                for (int mf = 0; mf < 5; ++mf)
#pragma unroll
                    for (int nf = 0; nf < 4; ++nf)
                        acc[mf][nf] = __builtin_amdgcn_mfma_f32_16x16x32_bf16(a[mf], bv[nf], acc[mf][nf], 0, 0, 0);
            }
        }
    }

#pragma unroll
    for (int mf = 0; mf < 5; ++mf) {
#pragma unroll
        for (int rg = 0; rg < 4; ++rg) {
            int co = mf * 16 + 4 * kg + rg;
            if (co < M) {
                float bvv = bias[co];
                float* op = out + (size_t)b * bstride + (size_t)co * cstride + boff;
#pragma unroll
                for (int nf = 0; nf < 4; ++nf) {
                    if (pn[nf] < L) {
                        float v = acc[mf][nf][rg] + bvv;
                        if (SIG) v = 1.f / (1.f + __expf(-v));
                        op[pn[nf]] = v;
                    }
                }
            }
        }
    }
}

// ---------------- DFL ----------------
__global__ void k_dfl(const float* __restrict__ logits, float* __restrict__ out,
                      int L, int scale_off) {
    int idx = blockIdx.x * 256 + threadIdx.x;
    int total = 16 * 4 * L;
    if (idx >= total) return;
    int p = idx % L, r = idx / L, f = r & 3, b = r >> 2;
    const float* lp = logits + ((size_t)b * 68 + f * 17) * L + p;
    float v[17], mx = -1e30f;
#pragma unroll
    for (int j = 0; j < 17; ++j) { v[j] = lp[(size_t)j * L]; mx = fmaxf(mx, v[j]); }
    float s = 0.f, d = 0.f;
#pragma unroll
    for (int j = 0; j < 17; ++j) {
        float e = __expf(v[j] - mx);
        s += e; d += e * (float)j;
    }
    out[OUT_REG + ((size_t)b * 4 + f) * 8400 + scale_off + p] = d / s;
}

// ---------------- anchors ----------------
__global__ void k_anchors(float* __restrict__ out) {
    int idx = blockIdx.x * 256 + threadIdx.x;
    if (idx >= 8400) return;
    int w, base; float s;
    if (idx < 400)       { w = 20; s = 32.f; base = 0; }
    else if (idx < 2000) { w = 40; s = 16.f; base = 400; }
    else                 { w = 80; s = 8.f;  base = 2000; }
    int r = idx - base;
    int row = r / w, col = r % w;
    out[OUT_ANC + (size_t)idx * 2]     = (float)col + 0.5f;
    out[OUT_ANC + (size_t)idx * 2 + 1] = (float)row + 0.5f;
    out[OUT_STR + idx] = s;
}

// ---------------------------------------------------------------------------
extern "C" void kernel_launch(void* const* d_in, const int* in_sizes, int n_in,
                              void* d_out, int out_size, void* d_ws, size_t ws_size,
                              hipStream_t stream) {
    const int B = 16;
    static const int Cs[3] = {1024, 512, 256};
    static const int Hs[3] = {20, 40, 80};
    static const int offs[3] = {0, 400, 2000};

    char* ws = (char*)d_ws;
    unsigned short* Bbuf = (unsigned short*)ws;                   // region1: 52,428,800 B
    float*          logits = (float*)ws;                          // region1 alias
    unsigned short* Xpad = (unsigned short*)(ws + 52428800);      // region2: 55,083,008 B
    unsigned short* Wb   = (unsigned short*)(ws + 107511808);     // 2 MB
    unsigned short* Wt   = (unsigned short*)(ws + 109608960);     // 1.47 MB
    float* avg = (float*)(ws + 111083520);
    float* gc  = (float*)(ws + 111149056);
    float* gr  = (float*)(ws + 111214592);
    float* out = (float*)d_out;

    for (int i = 0; i < 3; ++i) {
        const int base = i * 15;
        const float* feat = (const float*)d_in[base + 0];
        const float* cfw  = (const float*)d_in[base + 1];
        const float* cfb  = (const float*)d_in[base + 2];
        const float* ccw  = (const float*)d_in[base + 3];
        const float* cbs  = (const float*)d_in[base + 4];
        const float* cbb  = (const float*)d_in[base + 5];
        const float* rfw  = (const float*)d_in[base + 6];
        const float* rfb  = (const float*)d_in[base + 7];
        const float* rcw  = (const float*)d_in[base + 8];
        const float* rbs  = (const float*)d_in[base + 9];
        const float* rbb  = (const float*)d_in[base + 10];
        const float* pcw  = (const float*)d_in[base + 11];
        const float* pcb  = (const float*)d_in[base + 12];
        const float* prw  = (const float*)d_in[base + 13];
        const float* prb  = (const float*)d_in[base + 14];

        int C = Cs[i], H = Hs[i], W = H, L = H * W, Hp = H + 2, Wp = W + 2;

        long n16 = (long)B * Hp * Wp * C * 2 / 16;
        k_fill0<<<2048, 256, 0, stream>>>((uint4*)Xpad, n16);
        k_avgpool<<<B * C, 256, 0, stream>>>(feat, avg, L);
        k_gate<<<dim3(C / 16, 2), 256, 0, stream>>>(avg, cfw, cfb, rfw, rfb, gc, gr, C);

        dim3 gprep((L + 31) / 32, C / 32, B);
        dim3 gese((L + 127) / 128, C / 128, B);
        dim3 gcv((L + 255) / 256, B);

        // ---- cls branch ----
        k_wcvt<<<1024, 256, 0, stream>>>(ccw, Wb, C * C / 4);
        k_prep<true><<<gprep, 256, 0, stream>>>(feat, gc, Bbuf, Xpad, C, L, W, Wp, Hp);
        k_ese<true><<<gese, 256, 0, stream>>>(Bbuf, Wb, cbs, cbb, Xpad, C, L, W, Wp, Hp);
        k_wt3<<<(80 * 9 * C + 255) / 256, 256, 0, stream>>>(pcw, Wt, C, 80, 80 * 9 * C);
        k_conv3<true><<<gcv, 256, 0, stream>>>(Xpad, Wt, pcb, out, C, H, W, Hp, Wp, 80,
                                               (size_t)8400, (size_t)offs[i], (size_t)672000);

        // ---- reg branch ----
        k_wcvt<<<1024, 256, 0, stream>>>(rcw, Wb, C * C / 4);
        k_prep<false><<<gprep, 256, 0, stream>>>(feat, gr, Bbuf, Xpad, C, L, W, Wp, Hp);
        k_ese<false><<<gese, 256, 0, stream>>>(Bbuf, Wb, rbs, rbb, Xpad, C, L, W, Wp, Hp);
        k_wt3<<<(80 * 9 * C + 255) / 256, 256, 0, stream>>>(prw, Wt, C, 68, 80 * 9 * C);
        k_conv3<false><<<gcv, 256, 0, stream>>>(Xpad, Wt, prb, logits, C, H, W, Hp, Wp, 68,
                                                (size_t)L, (size_t)0, (size_t)(68 * L));

        k_dfl<<<(B * 4 * L + 255) / 256, 256, 0, stream>>>(logits, out, L, offs[i]);
    }
    k_anchors<<<33, 256, 0, stream>>>(out);
}

// Round 3
// 1641.334 us; speedup vs baseline: 6.7747x; 1.4370x over previous
//
#include <hip/hip_runtime.h>
#include <hip/hip_bf16.h>

// ---------------------------------------------------------------------------
// PPYOLOE head, bf16-MFMA version, split-K conv3.
// B=16; scales: (C,H,W) = (1024,20,20),(512,40,40),(256,80,80)
// d_out: cls [16,80,8400] f32 | reg [16,4,8400] f32 | anchors [8400,2] | stride [8400]
// ---------------------------------------------------------------------------

typedef short s8v __attribute__((ext_vector_type(8)));
typedef float f4v __attribute__((ext_vector_type(4)));

#define OUT_REG   10752000ull
#define OUT_ANC   11289600ull
#define OUT_STR   11306400ull

__device__ __forceinline__ unsigned short f2bf(float f) {
    unsigned u = __float_as_uint(f);
    u += 0x7fffu + ((u >> 16) & 1u);
    return (unsigned short)(u >> 16);
}
__device__ __forceinline__ float bf2f(unsigned short h) {
    return __uint_as_float(((unsigned)h) << 16);
}
__device__ __forceinline__ void gl16(const void* g, void* l) {
    __builtin_amdgcn_global_load_lds((const __attribute__((address_space(1))) void*)g,
                                     (__attribute__((address_space(3))) void*)l, 16, 0, 0);
}

// ---------------- zero-fill ----------------
__global__ void k_fill0(uint4* __restrict__ p, long n16) {
    uint4 z = make_uint4(0u, 0u, 0u, 0u);
    for (long i = blockIdx.x * 256 + threadIdx.x; i < n16; i += (long)gridDim.x * 256)
        p[i] = z;
}

// ---------------- avg pool over H*W ----------------
__global__ void k_avgpool(const float* __restrict__ feat, float* __restrict__ avg, int L) {
    int bc = blockIdx.x;
    const float* p = feat + (size_t)bc * L;
    float s = 0.f;
    for (int i = threadIdx.x; i < L; i += blockDim.x) s += p[i];
#pragma unroll
    for (int off = 32; off > 0; off >>= 1) s += __shfl_down(s, off, 64);
    __shared__ float wsum[4];
    int wid = threadIdx.x >> 6, lane = threadIdx.x & 63;
    if (lane == 0) wsum[wid] = s;
    __syncthreads();
    if (threadIdx.x == 0)
        avg[bc] = (wsum[0] + wsum[1] + wsum[2] + wsum[3]) / (float)L;
}

// ---------------- gate = sigmoid(fc_w @ avg + fc_b), both branches ----------
__global__ void k_gate(const float* __restrict__ avg,
                       const float* __restrict__ fcw_c, const float* __restrict__ fcb_c,
                       const float* __restrict__ fcw_r, const float* __restrict__ fcb_r,
                       float* __restrict__ gc, float* __restrict__ gr, int C) {
    const float* fcw = blockIdx.y ? fcw_r : fcw_c;
    const float* fcb = blockIdx.y ? fcb_r : fcb_c;
    float* g = blockIdx.y ? gr : gc;
    int col = threadIdx.x & 15;
    int b   = threadIdx.x >> 4;
    int co  = blockIdx.x * 16 + col;
    const float* wrow = fcw + (size_t)co * C;
    const float* arow = avg + (size_t)b * C;
    float s = fcb[co];
    for (int ci = 0; ci < C; ++ci) s += wrow[ci] * arow[ci];
    g[(size_t)b * C + co] = 1.f / (1.f + expf(-s));
}

// ---------------- weight conversions ----------------
__global__ void k_wcvt(const float* __restrict__ w, unsigned short* __restrict__ o, int n4) {
    for (int i = blockIdx.x * 256 + threadIdx.x; i < n4; i += gridDim.x * 256) {
        float4 v = ((const float4*)w)[i];
        ushort4 u = make_ushort4(f2bf(v.x), f2bf(v.y), f2bf(v.z), f2bf(v.w));
        ((ushort4*)o)[i] = u;
    }
}

// 3x3 weights: src OIHW [co][ci][tap] -> dst [80][tap*C + ci], zero-pad co>=M
__global__ void k_wt3(const float* __restrict__ src, unsigned short* __restrict__ dst,
                      int C, int M, int n) {
    int nineC = 9 * C;
    for (int idx = blockIdx.x * 256 + threadIdx.x; idx < n; idx += gridDim.x * 256) {
        int co = idx / nineC, r = idx - co * nineC;
        int tap = r / C, ci = r - tap * C;
        unsigned short v = 0;
        if (co < M)
            v = f2bf(src[(size_t)co * C * 9 + (size_t)ci * 9 + tap]);
        dst[idx] = v;
    }
}

// ---------------- prep: Bbuf[b][p][ci]=bf16(feat*gate); opt Xpad[p_pad][ci]=bf16(feat)
template<bool WR>
__global__ __launch_bounds__(256) void k_prep(const float* __restrict__ feat,
                                              const float* __restrict__ gate,
                                              unsigned short* __restrict__ Bbuf,
                                              unsigned short* __restrict__ Xpad,
                                              int C, int L, int W, int Wp, int Hp) {
    int b = blockIdx.z, ci0 = blockIdx.y * 32, p0 = blockIdx.x * 32;
    __shared__ float S[32][33];
    int t = threadIdx.x;
    {
        int cil = t >> 3, pl4 = (t & 7) * 4;
        int p = p0 + pl4;
        const float* src = feat + ((size_t)(b * C + ci0 + cil)) * L + p;
        float4 v = make_float4(0.f, 0.f, 0.f, 0.f);
        if (p + 3 < L) v = *(const float4*)src;
        else {
            if (p < L)     v.x = src[0];
            if (p + 1 < L) v.y = src[1];
            if (p + 2 < L) v.z = src[2];
            if (p + 3 < L) v.w = src[3];
        }
        S[cil][pl4] = v.x; S[cil][pl4 + 1] = v.y;
        S[cil][pl4 + 2] = v.z; S[cil][pl4 + 3] = v.w;
    }
    __syncthreads();
    int pl = t >> 3, ci4 = (t & 7) * 4;
    int p = p0 + pl;
    if (p < L) {
        float4 g = *(const float4*)(gate + (size_t)b * C + ci0 + ci4);
        float f0 = S[ci4][pl], f1 = S[ci4 + 1][pl], f2 = S[ci4 + 2][pl], f3 = S[ci4 + 3][pl];
        ushort4 ug = make_ushort4(f2bf(f0 * g.x), f2bf(f1 * g.y), f2bf(f2 * g.z), f2bf(f3 * g.w));
        *(ushort4*)(Bbuf + ((size_t)b * L + p) * C + ci0 + ci4) = ug;
        if (WR) {
            int y = p / W, x = p - y * W;
            ushort4 uf = make_ushort4(f2bf(f0), f2bf(f1), f2bf(f2), f2bf(f3));
            *(ushort4*)(Xpad + (((size_t)b * Hp + 1 + y) * Wp + 1 + x) * C + ci0 + ci4) = uf;
        }
    }
}

// ---------------- ESE 1x1 as MFMA GEMM ----------------
template<bool RES>
__global__ __launch_bounds__(256) void k_ese(const unsigned short* __restrict__ Ab,
                                             const unsigned short* __restrict__ Wm,
                                             const float* __restrict__ bns,
                                             const float* __restrict__ bnb,
                                             unsigned short* __restrict__ Xpad,
                                             int C, int L, int W, int Wp, int Hp) {
    int b = blockIdx.z;
    int p0 = blockIdx.x * 128, co0 = blockIdx.y * 128;
    __shared__ unsigned short As[128 * 32];
    __shared__ unsigned short Bs[128 * 32];
    int t = threadIdx.x, lane = t & 63, w = t >> 6;
    int l15 = lane & 15, kg = lane >> 4;
    int mbase = (w >> 1) * 64, nbase = (w & 1) * 64;
    int swb = ((kg ^ (l15 & 3) ^ ((l15 >> 2) & 3)) << 4);
    int slog = (t & 3) ^ ((t >> 2) & 3) ^ ((t >> 4) & 3);
    int r = t >> 2;
    size_t aRow = ((size_t)b * L + p0 + r) * C + 8 * slog;
    size_t bRow = ((size_t)(co0 + r)) * C + 8 * slog;
    size_t rstep = (size_t)64 * C;

    f4v acc[4][4];
#pragma unroll
    for (int i = 0; i < 4; ++i)
#pragma unroll
        for (int j = 0; j < 4; ++j) acc[i][j] = {0.f, 0.f, 0.f, 0.f};

    for (int k0 = 0; k0 < C; k0 += 32) {
        gl16(Ab + aRow + k0,         (char*)As + t * 16);
        gl16(Ab + aRow + rstep + k0, (char*)As + 4096 + t * 16);
        gl16(Wm + bRow + k0,         (char*)Bs + t * 16);
        gl16(Wm + bRow + rstep + k0, (char*)Bs + 4096 + t * 16);
        __syncthreads();
        s8v af[4], bv[4];
#pragma unroll
        for (int i = 0; i < 4; ++i)
            af[i] = *(const s8v*)((const char*)As + ((mbase + i * 16 + l15) << 6) + swb);
#pragma unroll
        for (int i = 0; i < 4; ++i)
            bv[i] = *(const s8v*)((const char*)Bs + ((nbase + i * 16 + l15) << 6) + swb);
#pragma unroll
        for (int mf = 0; mf < 4; ++mf)
#pragma unroll
            for (int nf = 0; nf < 4; ++nf)
                acc[mf][nf] = __builtin_amdgcn_mfma_f32_16x16x32_bf16(af[mf], bv[nf], acc[mf][nf], 0, 0, 0);
        __syncthreads();
    }

    float sv[4], bvv[4];
#pragma unroll
    for (int nf = 0; nf < 4; ++nf) {
        int co = co0 + nbase + nf * 16 + l15;
        sv[nf] = bns[co]; bvv[nf] = bnb[co];
    }
    int cobase = co0 + nbase + l15;
#pragma unroll
    for (int mf = 0; mf < 4; ++mf) {
#pragma unroll
        for (int rg = 0; rg < 4; ++rg) {
            int p = p0 + mbase + mf * 16 + 4 * kg + rg;
            if (p < L) {
                int y = p / W, x = p - y * W;
                size_t rowb = (((size_t)b * Hp + 1 + y) * Wp + 1 + x) * C + cobase;
#pragma unroll
                for (int nf = 0; nf < 4; ++nf) {
                    float v = acc[mf][nf][rg] * sv[nf] + bvv[nf];
                    v = v / (1.f + __expf(-v));
                    unsigned short* dst = Xpad + rowb + nf * 16;
                    if (RES) v += bf2f(*dst);
                    *dst = f2bf(v);
                }
            }
        }
    }
}

// ---------------- 3x3 conv: implicit MFMA GEMM, split-K over ci ------------
// grid: (ceil(L/256), B, NSPLIT). Raw f32 accum -> part (atomic if NSPLIT>1).
template<bool ATOMIC>
__global__ __launch_bounds__(256, 2) void k_conv3(const unsigned short* __restrict__ Xpad,
                                                  const unsigned short* __restrict__ Wt,
                                                  float* __restrict__ part,
                                                  int C, int KC, int H, int W,
                                                  int Hp, int Wp, int M) {
    int b = blockIdx.y;
    int L = H * W;
    int t = threadIdx.x, lane = t & 63, w = t >> 6;
    int l15 = lane & 15, kg = lane >> 4;
    int pw0 = blockIdx.x * 256 + w * 64;
    int nineC = 9 * C;
    int ciS = blockIdx.z * KC;

    int  pn[4];
    long basen[4];
#pragma unroll
    for (int nf = 0; nf < 4; ++nf) {
        int p = pw0 + nf * 16 + l15;
        pn[nf] = p;
        int pc = p < L ? p : L - 1;
        int y = pc / W, x = pc - y * W;
        basen[nf] = (((long)b * Hp + 1 + y) * Wp + 1 + x) * C + ciS + 8 * kg;
    }
    long wb[5];
#pragma unroll
    for (int mf = 0; mf < 5; ++mf)
        wb[mf] = (long)(mf * 16 + l15) * nineC + ciS + 8 * kg;

    f4v acc[5][4];
#pragma unroll
    for (int i = 0; i < 5; ++i)
#pragma unroll
        for (int j = 0; j < 4; ++j) acc[i][j] = {0.f, 0.f, 0.f, 0.f};

    for (int c0 = 0; c0 < KC; c0 += 32) {
#pragma unroll
        for (int ky = 0; ky < 3; ++ky) {
#pragma unroll
            for (int kx = 0; kx < 3; ++kx) {
                int tap = ky * 3 + kx;
                long toff = ((long)(ky - 1) * Wp + (kx - 1)) * C + c0;
                s8v a[5], bv[4];
#pragma unroll
                for (int mf = 0; mf < 5; ++mf)
                    a[mf] = *(const s8v*)(Wt + wb[mf] + tap * C + c0);
#pragma unroll
                for (int nf = 0; nf < 4; ++nf)
                    bv[nf] = *(const s8v*)(Xpad + basen[nf] + toff);
#pragma unroll
                for (int mf = 0; mf < 5; ++mf)
#pragma unroll
                    for (int nf = 0; nf < 4; ++nf)
                        acc[mf][nf] = __builtin_amdgcn_mfma_f32_16x16x32_bf16(a[mf], bv[nf], acc[mf][nf], 0, 0, 0);
            }
        }
    }

#pragma unroll
    for (int mf = 0; mf < 5; ++mf) {
#pragma unroll
        for (int rg = 0; rg < 4; ++rg) {
            int co = mf * 16 + 4 * kg + rg;
            if (co < M) {
                float* op = part + ((long)b * M + co) * L;
#pragma unroll
                for (int nf = 0; nf < 4; ++nf) {
                    if (pn[nf] < L) {
                        float v = acc[mf][nf][rg];
                        if (ATOMIC) unsafeAtomicAdd(op + pn[nf], v);
                        else        op[pn[nf]] = v;
                    }
                }
            }
        }
    }
}

// ---------------- cls activation: out = sigmoid(part + bias) ----------------
__global__ void k_actcls(const float* __restrict__ part, const float* __restrict__ bias,
                         float* __restrict__ out, int L, int off) {
    long n4 = (long)16 * 80 * L / 4;
    long Lq = L / 4;
    for (long i = blockIdx.x * 256 + threadIdx.x; i < n4; i += (long)gridDim.x * 256) {
        float4 v = ((const float4*)part)[i];
        int p4 = (int)(i % Lq) * 4;
        int co = (int)((i / Lq) % 80);
        int b  = (int)(i / (Lq * 80));
        float bb = bias[co];
        v.x = 1.f / (1.f + __expf(-(v.x + bb)));
        v.y = 1.f / (1.f + __expf(-(v.y + bb)));
        v.z = 1.f / (1.f + __expf(-(v.z + bb)));
        v.w = 1.f / (1.f + __expf(-(v.w + bb)));
        *(float4*)(out + (long)b * 672000 + (long)co * 8400 + off + p4) = v;
    }
}

// ---------------- DFL: softmax over 17 bins (+bias), integral ---------------
__global__ void k_dfl(const float* __restrict__ logits, const float* __restrict__ pb,
                      float* __restrict__ out, int L, int scale_off) {
    int idx = blockIdx.x * 256 + threadIdx.x;
    int total = 16 * 4 * L;
    if (idx >= total) return;
    int p = idx % L, r = idx / L, f = r & 3, b = r >> 2;
    const float* lp = logits + ((size_t)b * 68 + f * 17) * L + p;
    float v[17], mx = -1e30f;
#pragma unroll
    for (int j = 0; j < 17; ++j) {
        v[j] = lp[(size_t)j * L] + pb[f * 17 + j];
        mx = fmaxf(mx, v[j]);
    }
    float s = 0.f, d = 0.f;
#pragma unroll
    for (int j = 0; j < 17; ++j) {
        float e = __expf(v[j] - mx);
        s += e; d += e * (float)j;
    }
    out[OUT_REG + ((size_t)b * 4 + f) * 8400 + scale_off + p] = d / s;
}

// ---------------- anchors ----------------
__global__ void k_anchors(float* __restrict__ out) {
    int idx = blockIdx.x * 256 + threadIdx.x;
    if (idx >= 8400) return;
    int w, base; float s;
    if (idx < 400)       { w = 20; s = 32.f; base = 0; }
    else if (idx < 2000) { w = 40; s = 16.f; base = 400; }
    else                 { w = 80; s = 8.f;  base = 2000; }
    int r = idx - base;
    int row = r / w, col = r % w;
    out[OUT_ANC + (size_t)idx * 2]     = (float)col + 0.5f;
    out[OUT_ANC + (size_t)idx * 2 + 1] = (float)row + 0.5f;
    out[OUT_STR + idx] = s;
}

// ---------------------------------------------------------------------------
extern "C" void kernel_launch(void* const* d_in, const int* in_sizes, int n_in,
                              void* d_out, int out_size, void* d_ws, size_t ws_size,
                              hipStream_t stream) {
    const int B = 16;
    static const int Cs[3] = {1024, 512, 256};
    static const int Hs[3] = {20, 40, 80};
    static const int offs[3] = {0, 400, 2000};
    static const int NSs[3] = {16, 4, 1};

    char* ws = (char*)d_ws;
    unsigned short* Bbuf = (unsigned short*)ws;               // region1: 52,428,800 B
    float*          part = (float*)ws;                        // region1 alias (time-shared)
    unsigned short* Xpad = (unsigned short*)(ws + 52428800);  // region2: 55,083,008 B
    unsigned short* Wb   = (unsigned short*)(ws + 107511808);
    unsigned short* Wt   = (unsigned short*)(ws + 109608960);
    float* avg = (float*)(ws + 111083520);
    float* gc  = (float*)(ws + 111149056);
    float* gr  = (float*)(ws + 111214592);
    float* out = (float*)d_out;

    for (int i = 0; i < 3; ++i) {
        const int base = i * 15;
        const float* feat = (const float*)d_in[base + 0];
        const float* cfw  = (const float*)d_in[base + 1];
        const float* cfb  = (const float*)d_in[base + 2];
        const float* ccw  = (const float*)d_in[base + 3];
        const float* cbs  = (const float*)d_in[base + 4];
        const float* cbb  = (const float*)d_in[base + 5];
        const float* rfw  = (const float*)d_in[base + 6];
        const float* rfb  = (const float*)d_in[base + 7];
        const float* rcw  = (const float*)d_in[base + 8];
        const float* rbs  = (const float*)d_in[base + 9];
        const float* rbb  = (const float*)d_in[base + 10];
        const float* pcw  = (const float*)d_in[base + 11];
        const float* pcb  = (const float*)d_in[base + 12];
        const float* prw  = (const float*)d_in[base + 13];
        const float* prb  = (const float*)d_in[base + 14];

        int C = Cs[i], H = Hs[i], W = H, L = H * W, Hp = H + 2, Wp = W + 2;
        int NS = NSs[i], KC = C / NS;

        long n16 = (long)B * Hp * Wp * C * 2 / 16;
        k_fill0<<<2048, 256, 0, stream>>>((uint4*)Xpad, n16);
        k_avgpool<<<B * C, 256, 0, stream>>>(feat, avg, L);
        k_gate<<<dim3(C / 16, 2), 256, 0, stream>>>(avg, cfw, cfb, rfw, rfb, gc, gr, C);

        dim3 gprep((L + 31) / 32, C / 32, B);
        dim3 gese((L + 127) / 128, C / 128, B);
        dim3 gcv((L + 255) / 256, B, NS);

        // ---- cls branch ----
        k_wcvt<<<1024, 256, 0, stream>>>(ccw, Wb, C * C / 4);
        k_prep<true><<<gprep, 256, 0, stream>>>(feat, gc, Bbuf, Xpad, C, L, W, Wp, Hp);
        k_ese<true><<<gese, 256, 0, stream>>>(Bbuf, Wb, cbs, cbb, Xpad, C, L, W, Wp, Hp);
        k_wt3<<<(80 * 9 * C + 255) / 256, 256, 0, stream>>>(pcw, Wt, C, 80, 80 * 9 * C);
        if (NS > 1) {
            k_fill0<<<1024, 256, 0, stream>>>((uint4*)part, (long)80 * L * 4);
            k_conv3<true><<<gcv, 256, 0, stream>>>(Xpad, Wt, part, C, KC, H, W, Hp, Wp, 80);
        } else {
            k_conv3<false><<<gcv, 256, 0, stream>>>(Xpad, Wt, part, C, KC, H, W, Hp, Wp, 80);
        }
        k_actcls<<<1024, 256, 0, stream>>>(part, pcb, out, L, offs[i]);

        // ---- reg branch ----
        k_wcvt<<<1024, 256, 0, stream>>>(rcw, Wb, C * C / 4);
        k_prep<false><<<gprep, 256, 0, stream>>>(feat, gr, Bbuf, Xpad, C, L, W, Wp, Hp);
        k_ese<false><<<gese, 256, 0, stream>>>(Bbuf, Wb, rbs, rbb, Xpad, C, L, W, Wp, Hp);
        k_wt3<<<(80 * 9 * C + 255) / 256, 256, 0, stream>>>(prw, Wt, C, 68, 80 * 9 * C);
        if (NS > 1) {
            k_fill0<<<1024, 256, 0, stream>>>((uint4*)part, (long)68 * L * 4);
            k_conv3<true><<<gcv, 256, 0, stream>>>(Xpad, Wt, part, C, KC, H, W, Hp, Wp, 68);
        } else {
            k_conv3<false><<<gcv, 256, 0, stream>>>(Xpad, Wt, part, C, KC, H, W, Hp, Wp, 68);
        }
        k_dfl<<<(B * 4 * L + 255) / 256, 256, 0, stream>>>(part, prb, out, L, offs[i]);
    }
    k_anchors<<<33, 256, 0, stream>>>(out);
}

// Round 5
// 1561.138 us; speedup vs baseline: 7.1228x; 1.0514x over previous
//
#include <hip/hip_runtime.h>
#include <hip/hip_bf16.h>

// ---------------------------------------------------------------------------
// PPYOLOE head, bf16-MFMA, LDS-staged tiled conv3.
// B=16; scales: (C,H,W) = (1024,20,20),(512,40,40),(256,80,80)
// d_out: cls [16,80,8400] f32 | reg [16,4,8400] f32 | anchors [8400,2] | stride [8400]
// ---------------------------------------------------------------------------

typedef short s8v __attribute__((ext_vector_type(8)));
typedef float f4v __attribute__((ext_vector_type(4)));

#define OUT_REG   10752000ull
#define OUT_ANC   11289600ull
#define OUT_STR   11306400ull

__device__ __forceinline__ unsigned short f2bf(float f) {
    unsigned u = __float_as_uint(f);
    u += 0x7fffu + ((u >> 16) & 1u);
    return (unsigned short)(u >> 16);
}
__device__ __forceinline__ float bf2f(unsigned short h) {
    return __uint_as_float(((unsigned)h) << 16);
}
__device__ __forceinline__ void gl16(const void* g, void* l) {
    __builtin_amdgcn_global_load_lds((const __attribute__((address_space(1))) void*)g,
                                     (__attribute__((address_space(3))) void*)l, 16, 0, 0);
}

// ---------------- zero-fill (for part buffers) ----------------
__global__ void k_fill0(uint4* __restrict__ p, long n16) {
    uint4 z = make_uint4(0u, 0u, 0u, 0u);
    for (long i = blockIdx.x * 256 + threadIdx.x; i < n16; i += (long)gridDim.x * 256)
        p[i] = z;
}

// ---------------- zero only the halo border of Xpad ----------------
__global__ void k_fillhalo(unsigned short* __restrict__ Xpad, int Hp, int Wp, int C) {
    int rowC = Wp * C;
    long T8 = (long)(2 * rowC + 2 * (Hp - 2) * C) / 8;
    long n8 = 16 * T8;
    uint4 z = make_uint4(0u, 0u, 0u, 0u);
    for (long i = blockIdx.x * 256 + threadIdx.x; i < n8; i += (long)gridDim.x * 256) {
        int b = (int)(i / T8);
        long e = (i % T8) * 8;
        long addr;
        if (e < rowC) {                       // top row
            addr = ((long)b * Hp) * rowC + e;
        } else if (e < 2L * rowC) {           // bottom row
            addr = ((long)b * Hp + Hp - 1) * rowC + (e - rowC);
        } else {
            long e2 = e - 2L * rowC;
            int y = 1 + (int)(e2 / (2 * C));
            int r = (int)(e2 % (2 * C));
            int col = (r < C) ? 0 : (Wp - 1);
            int ci = (r < C) ? r : r - C;
            addr = (((long)b * Hp + y) * Wp + col) * (long)C + ci;
        }
        *(uint4*)(Xpad + addr) = z;
    }
}

// ---------------- avg pool over H*W ----------------
__global__ void k_avgpool(const float* __restrict__ feat, float* __restrict__ avg, int L) {
    int bc = blockIdx.x;
    const float* p = feat + (size_t)bc * L;
    float s = 0.f;
    for (int i = threadIdx.x; i < L; i += blockDim.x) s += p[i];
#pragma unroll
    for (int off = 32; off > 0; off >>= 1) s += __shfl_down(s, off, 64);
    __shared__ float wsum[4];
    int wid = threadIdx.x >> 6, lane = threadIdx.x & 63;
    if (lane == 0) wsum[wid] = s;
    __syncthreads();
    if (threadIdx.x == 0)
        avg[bc] = (wsum[0] + wsum[1] + wsum[2] + wsum[3]) / (float)L;
}

// ---------------- gate = sigmoid(fc_w @ avg + fc_b), both branches ----------
__global__ void k_gate(const float* __restrict__ avg,
                       const float* __restrict__ fcw_c, const float* __restrict__ fcb_c,
                       const float* __restrict__ fcw_r, const float* __restrict__ fcb_r,
                       float* __restrict__ gc, float* __restrict__ gr, int C) {
    const float* fcw = blockIdx.y ? fcw_r : fcw_c;
    const float* fcb = blockIdx.y ? fcb_r : fcb_c;
    float* g = blockIdx.y ? gr : gc;
    int col = threadIdx.x & 15;
    int b   = threadIdx.x >> 4;
    int co  = blockIdx.x * 16 + col;
    const float* wrow = fcw + (size_t)co * C;
    const float* arow = avg + (size_t)b * C;
    float s = fcb[co];
    for (int ci = 0; ci < C; ++ci) s += wrow[ci] * arow[ci];
    g[(size_t)b * C + co] = 1.f / (1.f + expf(-s));
}

// ---------------- weight conversions ----------------
__global__ void k_wcvt(const float* __restrict__ w, unsigned short* __restrict__ o, int n4) {
    for (int i = blockIdx.x * 256 + threadIdx.x; i < n4; i += gridDim.x * 256) {
        float4 v = ((const float4*)w)[i];
        ushort4 u = make_ushort4(f2bf(v.x), f2bf(v.y), f2bf(v.z), f2bf(v.w));
        ((ushort4*)o)[i] = u;
    }
}

// 3x3 weights: src OIHW [co][ci][tap] -> dst [80][tap*C + ci], zero-pad co>=M
__global__ void k_wt3(const float* __restrict__ src, unsigned short* __restrict__ dst,
                      int C, int M, int n) {
    int nineC = 9 * C;
    for (int idx = blockIdx.x * 256 + threadIdx.x; idx < n; idx += gridDim.x * 256) {
        int co = idx / nineC, r = idx - co * nineC;
        int tap = r / C, ci = r - tap * C;
        unsigned short v = 0;
        if (co < M)
            v = f2bf(src[(size_t)co * C * 9 + (size_t)ci * 9 + tap]);
        dst[idx] = v;
    }
}

// ---------------- prep: Bbuf[b][p][ci]=bf16(feat*gate); opt Xpad[p_pad][ci]=bf16(feat)
template<bool WR>
__global__ __launch_bounds__(256) void k_prep(const float* __restrict__ feat,
                                              const float* __restrict__ gate,
                                              unsigned short* __restrict__ Bbuf,
                                              unsigned short* __restrict__ Xpad,
                                              int C, int L, int W, int Wp, int Hp) {
    int b = blockIdx.z, ci0 = blockIdx.y * 32, p0 = blockIdx.x * 32;
    __shared__ float S[32][33];
    int t = threadIdx.x;
    {
        int cil = t >> 3, pl4 = (t & 7) * 4;
        int p = p0 + pl4;
        const float* src = feat + ((size_t)(b * C + ci0 + cil)) * L + p;
        float4 v = make_float4(0.f, 0.f, 0.f, 0.f);
        if (p + 3 < L) v = *(const float4*)src;
        else {
            if (p < L)     v.x = src[0];
            if (p + 1 < L) v.y = src[1];
            if (p + 2 < L) v.z = src[2];
            if (p + 3 < L) v.w = src[3];
        }
        S[cil][pl4] = v.x; S[cil][pl4 + 1] = v.y;
        S[cil][pl4 + 2] = v.z; S[cil][pl4 + 3] = v.w;
    }
    __syncthreads();
    int pl = t >> 3, ci4 = (t & 7) * 4;
    int p = p0 + pl;
    if (p < L) {
        float4 g = *(const float4*)(gate + (size_t)b * C + ci0 + ci4);
        float f0 = S[ci4][pl], f1 = S[ci4 + 1][pl], f2 = S[ci4 + 2][pl], f3 = S[ci4 + 3][pl];
        ushort4 ug = make_ushort4(f2bf(f0 * g.x), f2bf(f1 * g.y), f2bf(f2 * g.z), f2bf(f3 * g.w));
        *(ushort4*)(Bbuf + ((size_t)b * L + p) * C + ci0 + ci4) = ug;
        if (WR) {
            int y = p / W, x = p - y * W;
            ushort4 uf = make_ushort4(f2bf(f0), f2bf(f1), f2bf(f2), f2bf(f3));
            *(ushort4*)(Xpad + (((size_t)b * Hp + 1 + y) * Wp + 1 + x) * C + ci0 + ci4) = uf;
        }
    }
}

// ---------------- ESE 1x1 as MFMA GEMM ----------------
template<bool RES>
__global__ __launch_bounds__(256) void k_ese(const unsigned short* __restrict__ Ab,
                                             const unsigned short* __restrict__ Wm,
                                             const float* __restrict__ bns,
                                             const float* __restrict__ bnb,
                                             unsigned short* __restrict__ Xpad,
                                             int C, int L, int W, int Wp, int Hp) {
    int b = blockIdx.z;
    int p0 = blockIdx.x * 128, co0 = blockIdx.y * 128;
    __shared__ unsigned short As[128 * 32];
    __shared__ unsigned short Bs[128 * 32];
    int t = threadIdx.x, lane = t & 63, w = t >> 6;
    int l15 = lane & 15, kg = lane >> 4;
    int mbase = (w >> 1) * 64, nbase = (w & 1) * 64;
    int swb = ((kg ^ (l15 & 3) ^ ((l15 >> 2) & 3)) << 4);
    int slog = (t & 3) ^ ((t >> 2) & 3) ^ ((t >> 4) & 3);
    int r = t >> 2;
    size_t aRow = ((size_t)b * L + p0 + r) * C + 8 * slog;
    size_t bRow = ((size_t)(co0 + r)) * C + 8 * slog;
    size_t rstep = (size_t)64 * C;

    f4v acc[4][4];
#pragma unroll
    for (int i = 0; i < 4; ++i)
#pragma unroll
        for (int j = 0; j < 4; ++j) acc[i][j] = {0.f, 0.f, 0.f, 0.f};

    for (int k0 = 0; k0 < C; k0 += 32) {
        gl16(Ab + aRow + k0,         (char*)As + t * 16);
        gl16(Ab + aRow + rstep + k0, (char*)As + 4096 + t * 16);
        gl16(Wm + bRow + k0,         (char*)Bs + t * 16);
        gl16(Wm + bRow + rstep + k0, (char*)Bs + 4096 + t * 16);
        __syncthreads();
        s8v af[4], bv[4];
#pragma unroll
        for (int i = 0; i < 4; ++i)
            af[i] = *(const s8v*)((const char*)As + ((mbase + i * 16 + l15) << 6) + swb);
#pragma unroll
        for (int i = 0; i < 4; ++i)
            bv[i] = *(const s8v*)((const char*)Bs + ((nbase + i * 16 + l15) << 6) + swb);
#pragma unroll
        for (int mf = 0; mf < 4; ++mf)
#pragma unroll
            for (int nf = 0; nf < 4; ++nf)
                acc[mf][nf] = __builtin_amdgcn_mfma_f32_16x16x32_bf16(af[mf], bv[nf], acc[mf][nf], 0, 0, 0);
        __syncthreads();
    }

    float sv[4], bvv[4];
#pragma unroll
    for (int nf = 0; nf < 4; ++nf) {
        int co = co0 + nbase + nf * 16 + l15;
        sv[nf] = bns[co]; bvv[nf] = bnb[co];
    }
    int cobase = co0 + nbase + l15;
#pragma unroll
    for (int mf = 0; mf < 4; ++mf) {
#pragma unroll
        for (int rg = 0; rg < 4; ++rg) {
            int p = p0 + mbase + mf * 16 + 4 * kg + rg;
            if (p < L) {
                int y = p / W, x = p - y * W;
                size_t rowb = (((size_t)b * Hp + 1 + y) * Wp + 1 + x) * C + cobase;
#pragma unroll
                for (int nf = 0; nf < 4; ++nf) {
                    float v = acc[mf][nf][rg] * sv[nf] + bvv[nf];
                    v = v / (1.f + __expf(-v));
                    unsigned short* dst = Xpad + rowb + nf * 16;
                    if (RES) v += bf2f(*dst);
                    *dst = f2bf(v);
                }
            }
        }
    }
}

// ---------------- 3x3 conv: LDS-staged implicit MFMA GEMM, split-K ---------
// Block: 400 px = R=400/WT rows; 5 waves x 5 frags(16px). grid (L/400, B, NS).
// Per 32-ci chunk: stage (R+2)x(WT+2)x32 X-slab into LDS via global_load_lds,
// then 9 taps via rolling B-frag ring (row-offset reuse). f32 atomic partials.
template<int WT>
__global__ __launch_bounds__(320, 2) void k_conv3t(const unsigned short* __restrict__ Xpad,
                                                   const unsigned short* __restrict__ Wt,
                                                   float* __restrict__ part,
                                                   int C, int KC, int Hp, int Wp, int M) {
    constexpr int BR    = 80 / WT;       // rows per 80-px band
    constexpr int R     = 400 / WT;      // rows per block
    constexpr int LROWS = R + 2;
    constexpr int LCOLS = WT + 2;
    constexpr int UNITS = LROWS * LCOLS;     // 64B units in LDS
    constexpr int TOT   = UNITS * 4;         // 16B chunks to stage
    constexpr int NEWL  = (BR < 3) ? BR : 3; // new ring loads per band
    __shared__ char lds[UNITS * 64];

    const int b  = blockIdx.y;
    const int bx = blockIdx.x;
    const int L  = WT * WT;                  // H==W for all scales
    const int t  = threadIdx.x, lane = t & 63, w = t >> 6;
    const int l15 = lane & 15, kg = lane >> 4;
    const int ciS = blockIdx.z * KC;
    const int nineC = 9 * C;
    const int y0 = bx * R;                   // Xpad row of LDS row 0 (= real y0-1 +1)

    // per-lane geometry: frag i covers px = bx*400 + i*80 + w*16 + l15
    const int lp0  = w * 16 + l15;           // in [0,80)
    const int ly00 = lp0 / WT;               // base row within band
    const int lx0  = lp0 % WT;

    long wbase[5];
#pragma unroll
    for (int m = 0; m < 5; ++m)
        wbase[m] = (long)(m * 16 + l15) * nineC + ciS + 8 * kg;

    f4v acc[5][5];
#pragma unroll
    for (int m = 0; m < 5; ++m)
#pragma unroll
        for (int i = 0; i < 5; ++i) acc[m][i] = {0.f, 0.f, 0.f, 0.f};

    const char* ldsw = lds + (kg << 4);      // + slot XOR applied per-read

    for (int c0 = 0; c0 < KC; c0 += 32) {
        // ---- stage X slab: rows [y0 .. y0+R+1] x [0..Wp) x 32ci ----
        __syncthreads();
#pragma unroll
        for (int it = 0; it < (TOT + 319) / 320; ++it) {
            int c = it * 320 + t;
            if (c < TOT) {
                int q = c >> 2, slot = c & 3;
                int row = q / LCOLS, col = q % LCOLS;
                int srcslot = slot ^ (q & 3) ^ ((q >> 2) & 3);
                const unsigned short* src = Xpad +
                    (((size_t)b * Hp + y0 + row) * Wp + col) * C + ciS + c0 + srcslot * 8;
                gl16(src, lds + (it * 320 + (t & ~63)) * 16);
            }
        }
        __syncthreads();

        // ---- 9 taps ----
#pragma unroll
        for (int kx = 0; kx < 3; ++kx) {
            s8v a[3][5];
#pragma unroll
            for (int ky = 0; ky < 3; ++ky)
#pragma unroll
                for (int m = 0; m < 5; ++m)
                    a[ky][m] = *(const s8v*)(Wt + wbase[m] + (ky * 3 + kx) * C + c0);

            s8v ring[4];
            // LOADB(roff): lane reads 16B at unit u=(ly00+roff)*LCOLS+lx0+kx
#define LOADB(roff)                                                              \
            {                                                                    \
                int u_ = (ly00 + (roff)) * LCOLS + lx0 + kx;                     \
                ring[(roff) & 3] = *(const s8v*)(ldsw + (u_ << 6) +              \
                                   (((u_ & 3) ^ ((u_ >> 2) & 3)) << 4));         \
            }
            LOADB(0); LOADB(1); LOADB(2);
#pragma unroll
            for (int i = 0; i < 5; ++i) {
                if (i > 0) {
#pragma unroll
                    for (int d = 3 - NEWL; d < 3; ++d) LOADB(BR * i + d);
                }
#pragma unroll
                for (int ky = 0; ky < 3; ++ky) {
                    s8v bf = ring[(BR * i + ky) & 3];
#pragma unroll
                    for (int m = 0; m < 5; ++m)
                        acc[m][i] = __builtin_amdgcn_mfma_f32_16x16x32_bf16(a[ky][m], bf, acc[m][i], 0, 0, 0);
                }
            }
#undef LOADB
        }
    }

    // ---- output: atomic accumulate partials ----
    const int pbase = bx * 400 + w * 16 + l15;
#pragma unroll
    for (int m = 0; m < 5; ++m) {
#pragma unroll
        for (int rg = 0; rg < 4; ++rg) {
            int co = m * 16 + 4 * kg + rg;
            if (co < M) {
                float* op = part + ((long)b * M + co) * L + pbase;
#pragma unroll
                for (int i = 0; i < 5; ++i)
                    unsafeAtomicAdd(op + i * 80, acc[m][i][rg]);
            }
        }
    }
}

// ---------------- cls activation: out = sigmoid(part + bias) ----------------
__global__ void k_actcls(const float* __restrict__ part, const float* __restrict__ bias,
                         float* __restrict__ out, int L, int off) {
    long n4 = (long)16 * 80 * L / 4;
    long Lq = L / 4;
    for (long i = blockIdx.x * 256 + threadIdx.x; i < n4; i += (long)gridDim.x * 256) {
        float4 v = ((const float4*)part)[i];
        int p4 = (int)(i % Lq) * 4;
        int co = (int)((i / Lq) % 80);
        int b  = (int)(i / (Lq * 80));
        float bb = bias[co];
        v.x = 1.f / (1.f + __expf(-(v.x + bb)));
        v.y = 1.f / (1.f + __expf(-(v.y + bb)));
        v.z = 1.f / (1.f + __expf(-(v.z + bb)));
        v.w = 1.f / (1.f + __expf(-(v.w + bb)));
        *(float4*)(out + (long)b * 672000 + (long)co * 8400 + off + p4) = v;
    }
}

// ---------------- DFL: softmax over 17 bins (+bias), integral ---------------
__global__ void k_dfl(const float* __restrict__ logits, const float* __restrict__ pb,
                      float* __restrict__ out, int L, int scale_off) {
    int idx = blockIdx.x * 256 + threadIdx.x;
    int total = 16 * 4 * L;
    if (idx >= total) return;
    int p = idx % L, r = idx / L, f = r & 3, b = r >> 2;
    const float* lp = logits + ((size_t)b * 68 + f * 17) * L + p;
    float v[17], mx = -1e30f;
#pragma unroll
    for (int j = 0; j < 17; ++j) {
        v[j] = lp[(size_t)j * L] + pb[f * 17 + j];
        mx = fmaxf(mx, v[j]);
    }
    float s = 0.f, d = 0.f;
#pragma unroll
    for (int j = 0; j < 17; ++j) {
        float e = __expf(v[j] - mx);
        s += e; d += e * (float)j;
    }
    out[OUT_REG + ((size_t)b * 4 + f) * 8400 + scale_off + p] = d / s;
}

// ---------------- anchors ----------------
__global__ void k_anchors(float* __restrict__ out) {
    int idx = blockIdx.x * 256 + threadIdx.x;
    if (idx >= 8400) return;
    int w, base; float s;
    if (idx < 400)       { w = 20; s = 32.f; base = 0; }
    else if (idx < 2000) { w = 40; s = 16.f; base = 400; }
    else                 { w = 80; s = 8.f;  base = 2000; }
    int r = idx - base;
    int row = r / w, col = r % w;
    out[OUT_ANC + (size_t)idx * 2]     = (float)col + 0.5f;
    out[OUT_ANC + (size_t)idx * 2 + 1] = (float)row + 0.5f;
    out[OUT_STR + idx] = s;
}

// ---------------------------------------------------------------------------
extern "C" void kernel_launch(void* const* d_in, const int* in_sizes, int n_in,
                              void* d_out, int out_size, void* d_ws, size_t ws_size,
                              hipStream_t stream) {
    const int B = 16;
    static const int Cs[3] = {1024, 512, 256};
    static const int Hs[3] = {20, 40, 80};
    static const int offs[3] = {0, 400, 2000};
    static const int NSs[3] = {32, 8, 2};

    char* ws = (char*)d_ws;
    unsigned short* Bbuf = (unsigned short*)ws;               // region1: 52,428,800 B
    float*          part = (float*)ws;                        // region1 alias (time-shared)
    unsigned short* Xpad = (unsigned short*)(ws + 52428800);  // region2: 55,083,008 B
    unsigned short* Wb   = (unsigned short*)(ws + 107511808);
    unsigned short* Wt   = (unsigned short*)(ws + 109608960);
    float* avg = (float*)(ws + 111083520);
    float* gc  = (float*)(ws + 111149056);
    float* gr  = (float*)(ws + 111214592);
    float* out = (float*)d_out;

    for (int i = 0; i < 3; ++i) {
        const int base = i * 15;
        const float* feat = (const float*)d_in[base + 0];
        const float* cfw  = (const float*)d_in[base + 1];
        const float* cfb  = (const float*)d_in[base + 2];
        const float* ccw  = (const float*)d_in[base + 3];
        const float* cbs  = (const float*)d_in[base + 4];
        const float* cbb  = (const float*)d_in[base + 5];
        const float* rfw  = (const float*)d_in[base + 6];
        const float* rfb  = (const float*)d_in[base + 7];
        const float* rcw  = (const float*)d_in[base + 8];
        const float* rbs  = (const float*)d_in[base + 9];
        const float* rbb  = (const float*)d_in[base + 10];
        const float* pcw  = (const float*)d_in[base + 11];
        const float* pcb  = (const float*)d_in[base + 12];
        const float* prw  = (const float*)d_in[base + 13];
        const float* prb  = (const float*)d_in[base + 14];

        int C = Cs[i], H = Hs[i], W = H, L = H * W, Hp = H + 2, Wp = W + 2;
        int NS = NSs[i], KC = C / NS;

        k_fillhalo<<<512, 256, 0, stream>>>(Xpad, Hp, Wp, C);
        k_avgpool<<<B * C, 256, 0, stream>>>(feat, avg, L);
        k_gate<<<dim3(C / 16, 2), 256, 0, stream>>>(avg, cfw, cfb, rfw, rfb, gc, gr, C);

        dim3 gprep((L + 31) / 32, C / 32, B);
        dim3 gese((L + 127) / 128, C / 128, B);
        dim3 gcv(L / 400, B, NS);

        // ---- cls branch ----
        k_wcvt<<<1024, 256, 0, stream>>>(ccw, Wb, C * C / 4);
        k_prep<true><<<gprep, 256, 0, stream>>>(feat, gc, Bbuf, Xpad, C, L, W, Wp, Hp);
        k_ese<true><<<gese, 256, 0, stream>>>(Bbuf, Wb, cbs, cbb, Xpad, C, L, W, Wp, Hp);
        k_wt3<<<(80 * 9 * C + 255) / 256, 256, 0, stream>>>(pcw, Wt, C, 80, 80 * 9 * C);
        k_fill0<<<1024, 256, 0, stream>>>((uint4*)part, (long)B * 80 * L / 4);
        if (i == 0)      k_conv3t<20><<<gcv, 320, 0, stream>>>(Xpad, Wt, part, C, KC, Hp, Wp, 80);
        else if (i == 1) k_conv3t<40><<<gcv, 320, 0, stream>>>(Xpad, Wt, part, C, KC, Hp, Wp, 80);
        else             k_conv3t<80><<<gcv, 320, 0, stream>>>(Xpad, Wt, part, C, KC, Hp, Wp, 80);
        k_actcls<<<1024, 256, 0, stream>>>(part, pcb, out, L, offs[i]);

        // ---- reg branch ----
        k_wcvt<<<1024, 256, 0, stream>>>(rcw, Wb, C * C / 4);
        k_prep<false><<<gprep, 256, 0, stream>>>(feat, gr, Bbuf, Xpad, C, L, W, Wp, Hp);
        k_ese<false><<<gese, 256, 0, stream>>>(Bbuf, Wb, rbs, rbb, Xpad, C, L, W, Wp, Hp);
        k_wt3<<<(80 * 9 * C + 255) / 256, 256, 0, stream>>>(prw, Wt, C, 68, 80 * 9 * C);
        k_fill0<<<1024, 256, 0, stream>>>((uint4*)part, (long)B * 68 * L / 4);
        if (i == 0)      k_conv3t<20><<<gcv, 320, 0, stream>>>(Xpad, Wt, part, C, KC, Hp, Wp, 68);
        else if (i == 1) k_conv3t<40><<<gcv, 320, 0, stream>>>(Xpad, Wt, part, C, KC, Hp, Wp, 68);
        else             k_conv3t<80><<<gcv, 320, 0, stream>>>(Xpad, Wt, part, C, KC, Hp, Wp, 68);
        k_dfl<<<(B * 4 * L + 255) / 256, 256, 0, stream>>>(part, prb, out, L, offs[i]);
    }
    k_anchors<<<33, 256, 0, stream>>>(out);
}